// Round 1
// baseline (410.745 us; speedup 1.0000x reference)
//
#include <hip/hip_runtime.h>
#include <math.h>

#define NPTS 65536  // N per batch (fixed by problem)

__device__ __forceinline__ float lrelu(float x) {
  // leaky_relu(x, 0.2) == 0.6*x + 0.4*|x| ; ~1e-7 rel err, 2 VALU ops
  return fmaf(0.4f, fabsf(x), 0.6f * x);
}

// x1 = leaky(features @ w_init^T + b_init) : (BN,64) -> (BN,16)
__global__ __launch_bounds__(256) void k_init(
    const float* __restrict__ feats, const float* __restrict__ w,
    const float* __restrict__ bia, float* __restrict__ x1, int BN) {
  __shared__ float wt[64 * 16];  // wt[i*16+o] = w[o*64+i]
  int t = threadIdx.x;
  for (int e = t; e < 1024; e += 256) {
    int o = e >> 6, i = e & 63;
    wt[i * 16 + o] = w[e];
  }
  __syncthreads();
  int p = blockIdx.x * 256 + t;
  if (p >= BN) return;
  float acc[16];
#pragma unroll
  for (int o = 0; o < 16; ++o) acc[o] = bia[o];
  const float* xr = feats + (size_t)p * 64;
#pragma unroll 8
  for (int i = 0; i < 64; ++i) {
    float xi = xr[i];
    const float4* w4 = (const float4*)&wt[i * 16];
#pragma unroll
    for (int q = 0; q < 4; ++q) {
      float4 wv = w4[q];
      acc[q * 4 + 0] = fmaf(xi, wv.x, acc[q * 4 + 0]);
      acc[q * 4 + 1] = fmaf(xi, wv.y, acc[q * 4 + 1]);
      acc[q * 4 + 2] = fmaf(xi, wv.z, acc[q * 4 + 2]);
      acc[q * 4 + 3] = fmaf(xi, wv.w, acc[q * 4 + 3]);
    }
  }
  float4* op = (float4*)(x1 + (size_t)p * 16);
#pragma unroll
  for (int q = 0; q < 4; ++q) {
    float4 v;
    v.x = lrelu(acc[q * 4 + 0]);
    v.y = lrelu(acc[q * 4 + 1]);
    v.z = lrelu(acc[q * 4 + 2]);
    v.w = lrelu(acc[q * 4 + 3]);
    op[q] = v;
  }
}

// LFA: out[p] = [ mean_k leaky(geo @ w^T + b) , mean_k fin[idx[p,k]] ]
// geo = (rel.x, rel.y, rel.z, |rel|), rel = pts[p] - pts[neighbor]
template <int CIN, int CMLP>
__global__ __launch_bounds__(256) void k_lfa(
    const float* __restrict__ pts, const float* __restrict__ fin,
    const int* __restrict__ idx, const float* __restrict__ w,
    const float* __restrict__ bia, float* __restrict__ out, int BN) {
  __shared__ float4 ws[CMLP];  // one float4 row of w per output channel
  int t = threadIdx.x;
  if (t < CMLP) ws[t] = make_float4(w[t * 4 + 0], w[t * 4 + 1], w[t * 4 + 2], w[t * 4 + 3]);
  __syncthreads();
  int p = blockIdx.x * 256 + t;
  if (p >= BN) return;
  int base = p & ~(NPTS - 1);  // b*N
  const float* mp = pts + (size_t)p * 3;
  float mx = mp[0], my = mp[1], mz = mp[2];
  float br[CMLP];
#pragma unroll
  for (int o = 0; o < CMLP; ++o) br[o] = bia[o];
  float macc[CMLP], facc[CIN];
#pragma unroll
  for (int o = 0; o < CMLP; ++o) macc[o] = 0.f;
#pragma unroll
  for (int c = 0; c < CIN; ++c) facc[c] = 0.f;
  const int4* iv4 = (const int4*)(idx + (size_t)p * 32);
#pragma unroll 2
  for (int kk = 0; kk < 8; ++kk) {
    int4 iv = iv4[kk];
    int js[4] = {iv.x, iv.y, iv.z, iv.w};
#pragma unroll
    for (int u = 0; u < 4; ++u) {
      int j = base + js[u];
      const float* pj = pts + (size_t)j * 3;
      float rx = mx - pj[0], ry = my - pj[1], rz = mz - pj[2];
      float d = sqrtf(fmaf(rx, rx, fmaf(ry, ry, rz * rz)));
#pragma unroll
      for (int o = 0; o < CMLP; ++o) {
        float4 wv = ws[o];
        float s = fmaf(rx, wv.x, fmaf(ry, wv.y, fmaf(rz, wv.z, fmaf(d, wv.w, br[o]))));
        macc[o] += lrelu(s);
      }
      const float4* fj = (const float4*)(fin + (size_t)j * CIN);
#pragma unroll
      for (int c4 = 0; c4 < CIN / 4; ++c4) {
        float4 fv = fj[c4];
        facc[c4 * 4 + 0] += fv.x;
        facc[c4 * 4 + 1] += fv.y;
        facc[c4 * 4 + 2] += fv.z;
        facc[c4 * 4 + 3] += fv.w;
      }
    }
  }
  const float inv = 1.0f / 32.0f;
  float4* op = (float4*)(out + (size_t)p * (CMLP + CIN));
#pragma unroll
  for (int q = 0; q < CMLP / 4; ++q) {
    op[q] = make_float4(macc[q * 4 + 0] * inv, macc[q * 4 + 1] * inv,
                        macc[q * 4 + 2] * inv, macc[q * 4 + 3] * inv);
  }
#pragma unroll
  for (int q = 0; q < CIN / 4; ++q) {
    op[CMLP / 4 + q] = make_float4(facc[q * 4 + 0] * inv, facc[q * 4 + 1] * inv,
                                   facc[q * 4 + 2] * inv, facc[q * 4 + 3] * inv);
  }
}

// out = leaky(x3 @ wf^T + bf) + leaky(feats @ wr^T + br)   (in-place safe on x3==out)
__global__ __launch_bounds__(256) void k_final(
    const float* __restrict__ x3, const float* __restrict__ feats,
    const float* __restrict__ wf, const float* __restrict__ bf,
    const float* __restrict__ wr, const float* __restrict__ brs,
    float* __restrict__ out, int BN) {
  __shared__ float wtf[4096];  // wtf[i*64+o] = wf[o*64+i]
  __shared__ float wtr[4096];
  int t = threadIdx.x;
  for (int e = t; e < 4096; e += 256) {
    int o = e >> 6, i = e & 63;
    wtf[i * 64 + o] = wf[e];
    wtr[i * 64 + o] = wr[e];
  }
  __syncthreads();
  int p = blockIdx.x * 256 + t;
  if (p >= BN) return;
  float acc[64];
#pragma unroll
  for (int o = 0; o < 64; ++o) acc[o] = bf[o];
  const float* xr = x3 + (size_t)p * 64;
#pragma unroll 2
  for (int i = 0; i < 64; ++i) {
    float xi = xr[i];
    const float4* w4 = (const float4*)&wtf[i * 64];
#pragma unroll
    for (int q = 0; q < 16; ++q) {
      float4 wv = w4[q];
      acc[q * 4 + 0] = fmaf(xi, wv.x, acc[q * 4 + 0]);
      acc[q * 4 + 1] = fmaf(xi, wv.y, acc[q * 4 + 1]);
      acc[q * 4 + 2] = fmaf(xi, wv.z, acc[q * 4 + 2]);
      acc[q * 4 + 3] = fmaf(xi, wv.w, acc[q * 4 + 3]);
    }
  }
  float y[64];
#pragma unroll
  for (int o = 0; o < 64; ++o) y[o] = lrelu(acc[o]);
#pragma unroll
  for (int o = 0; o < 64; ++o) acc[o] = brs[o];
  const float* fr = feats + (size_t)p * 64;
#pragma unroll 2
  for (int i = 0; i < 64; ++i) {
    float xi = fr[i];
    const float4* w4 = (const float4*)&wtr[i * 64];
#pragma unroll
    for (int q = 0; q < 16; ++q) {
      float4 wv = w4[q];
      acc[q * 4 + 0] = fmaf(xi, wv.x, acc[q * 4 + 0]);
      acc[q * 4 + 1] = fmaf(xi, wv.y, acc[q * 4 + 1]);
      acc[q * 4 + 2] = fmaf(xi, wv.z, acc[q * 4 + 2]);
      acc[q * 4 + 3] = fmaf(xi, wv.w, acc[q * 4 + 3]);
    }
  }
  float4* op = (float4*)(out + (size_t)p * 64);
#pragma unroll
  for (int q = 0; q < 16; ++q) {
    float4 v;
    v.x = y[q * 4 + 0] + lrelu(acc[q * 4 + 0]);
    v.y = y[q * 4 + 1] + lrelu(acc[q * 4 + 1]);
    v.z = y[q * 4 + 2] + lrelu(acc[q * 4 + 2]);
    v.w = y[q * 4 + 3] + lrelu(acc[q * 4 + 3]);
    op[q] = v;
  }
}

extern "C" void kernel_launch(void* const* d_in, const int* in_sizes, int n_in,
                              void* d_out, int out_size, void* d_ws, size_t ws_size,
                              hipStream_t stream) {
  const float* pts    = (const float*)d_in[0];
  const float* feats  = (const float*)d_in[1];
  const int*   idx    = (const int*)d_in[2];
  const float* w_init = (const float*)d_in[3];
  const float* b_init = (const float*)d_in[4];
  const float* w_l1   = (const float*)d_in[5];
  const float* b_l1   = (const float*)d_in[6];
  const float* w_l2   = (const float*)d_in[7];
  const float* b_l2   = (const float*)d_in[8];
  const float* w_f    = (const float*)d_in[9];
  const float* b_f    = (const float*)d_in[10];
  const float* w_r    = (const float*)d_in[11];
  const float* b_r    = (const float*)d_in[12];
  float* out = (float*)d_out;

  int BN = in_sizes[2] / 32;  // B*N = 131072
  float* x1 = (float*)d_ws;                // BN*16 f32 = 8 MB
  float* x2 = x1 + (size_t)BN * 16;        // BN*32 f32 = 16 MB
  int blocks = (BN + 255) / 256;

  k_init<<<blocks, 256, 0, stream>>>(feats, w_init, b_init, x1, BN);
  k_lfa<16, 16><<<blocks, 256, 0, stream>>>(pts, x1, idx, w_l1, b_l1, x2, BN);
  // x3 lives in d_out; k_final consumes it row-pointwise in place.
  k_lfa<32, 32><<<blocks, 256, 0, stream>>>(pts, x2, idx, w_l2, b_l2, out, BN);
  k_final<<<blocks, 256, 0, stream>>>(out, feats, w_f, b_f, w_r, b_r, out, BN);
}

// Round 2
// 343.465 us; speedup vs baseline: 1.1959x; 1.1959x over previous
//
#include <hip/hip_runtime.h>
#include <math.h>

#define NPTS 65536  // N per batch (fixed by problem)

__device__ __forceinline__ float lrelu(float x) {
  // leaky_relu(x, 0.2) == 0.6*x + 0.4*|x| ; ~1e-7 rel err, 2 VALU ops
  return fmaf(0.4f, fabsf(x), 0.6f * x);
}

// x1 = leaky(features @ w_init^T + b_init) : (BN,64) -> (BN,16)
// also builds the padded float4 point table pts4[p] = (x,y,z,0)
__global__ __launch_bounds__(256) void k_init(
    const float* __restrict__ feats, const float* __restrict__ w,
    const float* __restrict__ bia, float* __restrict__ x1,
    const float* __restrict__ pts, float4* __restrict__ pts4, int BN) {
  __shared__ float wt[64 * 16];  // wt[i*16+o] = w[o*64+i]
  int t = threadIdx.x;
  for (int e = t; e < 1024; e += 256) {
    int o = e >> 6, i = e & 63;
    wt[i * 16 + o] = w[e];
  }
  __syncthreads();
  int p = blockIdx.x * 256 + t;
  if (p >= BN) return;
  // padded point table
  const float* pp = pts + (size_t)p * 3;
  pts4[p] = make_float4(pp[0], pp[1], pp[2], 0.0f);
  float acc[16];
#pragma unroll
  for (int o = 0; o < 16; ++o) acc[o] = bia[o];
  const float* xr = feats + (size_t)p * 64;
#pragma unroll 8
  for (int i = 0; i < 64; ++i) {
    float xi = xr[i];
    const float4* w4 = (const float4*)&wt[i * 16];
#pragma unroll
    for (int q = 0; q < 4; ++q) {
      float4 wv = w4[q];
      acc[q * 4 + 0] = fmaf(xi, wv.x, acc[q * 4 + 0]);
      acc[q * 4 + 1] = fmaf(xi, wv.y, acc[q * 4 + 1]);
      acc[q * 4 + 2] = fmaf(xi, wv.z, acc[q * 4 + 2]);
      acc[q * 4 + 3] = fmaf(xi, wv.w, acc[q * 4 + 3]);
    }
  }
  float4* op = (float4*)(x1 + (size_t)p * 16);
#pragma unroll
  for (int q = 0; q < 4; ++q) {
    float4 v;
    v.x = lrelu(acc[q * 4 + 0]);
    v.y = lrelu(acc[q * 4 + 1]);
    v.z = lrelu(acc[q * 4 + 2]);
    v.w = lrelu(acc[q * 4 + 3]);
    op[q] = v;
  }
}

// LFA, 4 threads per point, split by OUTPUT CHANNEL (no cross-lane reduce):
// lane sub owns MLP outputs [sub*CMLP/4, ...) and feat channels [sub*CIN/4, ...).
// out[p] = [ mean_k leaky(geo @ w^T + b) , mean_k fin[idx[p,k]] ]
template <int CIN, int CMLP>
__global__ __launch_bounds__(256) void k_lfa(
    const float4* __restrict__ pts4, const float* __restrict__ fin,
    const int* __restrict__ idx, const float* __restrict__ w,
    const float* __restrict__ bia, float* __restrict__ out, int BN) {
  constexpr int CM4 = CMLP / 4;  // mlp outputs per sub-lane (4 or 8)
  constexpr int CF = CIN / 4;    // feat channels per sub-lane (4 or 8 floats)
  int t = threadIdx.x;
  int p = blockIdx.x * 64 + (t >> 2);
  int sub = t & 3;
  if (p >= BN) return;
  int base = p & ~(NPTS - 1);  // b*N
  float4 mp = pts4[p];
  // this lane's slice of the 4-wide MLP weights + bias, in registers
  float4 wreg[CM4];
  float breg[CM4];
  const float4* wrow = (const float4*)w + sub * CM4;
#pragma unroll
  for (int o = 0; o < CM4; ++o) {
    wreg[o] = wrow[o];
    breg[o] = bia[sub * CM4 + o];
  }
  float macc[CM4], facc[CF];
#pragma unroll
  for (int o = 0; o < CM4; ++o) macc[o] = 0.f;
#pragma unroll
  for (int c = 0; c < CF; ++c) facc[c] = 0.f;
  const int4* iv4 = (const int4*)(idx + (size_t)p * 32);
#pragma unroll 2
  for (int kk = 0; kk < 8; ++kk) {
    int4 iv = iv4[kk];
    int js[4] = {iv.x, iv.y, iv.z, iv.w};
#pragma unroll
    for (int u = 0; u < 4; ++u) {
      int j = base + js[u];
      float4 pj = pts4[j];
      float rx = mp.x - pj.x, ry = mp.y - pj.y, rz = mp.z - pj.z;
      float d = sqrtf(fmaf(rx, rx, fmaf(ry, ry, rz * rz)));
#pragma unroll
      for (int o = 0; o < CM4; ++o) {
        float4 wv = wreg[o];
        float s = fmaf(rx, wv.x, fmaf(ry, wv.y, fmaf(rz, wv.z, fmaf(d, wv.w, breg[o]))));
        macc[o] += lrelu(s);
      }
      // group-coalesced: 4 sub-lanes cover the neighbor's full row
      const float4* fj = (const float4*)(fin + (size_t)j * CIN) + sub * (CF / 4);
#pragma unroll
      for (int c4 = 0; c4 < CF / 4; ++c4) {
        float4 fv = fj[c4];
        facc[c4 * 4 + 0] += fv.x;
        facc[c4 * 4 + 1] += fv.y;
        facc[c4 * 4 + 2] += fv.z;
        facc[c4 * 4 + 3] += fv.w;
      }
    }
  }
  const float inv = 1.0f / 32.0f;
  float* orow = out + (size_t)p * (CMLP + CIN);
  float* om = orow + sub * CM4;
#pragma unroll
  for (int q = 0; q < CM4 / 4; ++q) {
    ((float4*)om)[q] = make_float4(macc[q * 4 + 0] * inv, macc[q * 4 + 1] * inv,
                                   macc[q * 4 + 2] * inv, macc[q * 4 + 3] * inv);
  }
  float* of = orow + CMLP + sub * CF;
#pragma unroll
  for (int q = 0; q < CF / 4; ++q) {
    ((float4*)of)[q] = make_float4(facc[q * 4 + 0] * inv, facc[q * 4 + 1] * inv,
                                   facc[q * 4 + 2] * inv, facc[q * 4 + 3] * inv);
  }
}

// out = leaky(x3 @ wf^T + bf) + leaky(feats @ wr^T + br)   (in-place safe on x3==out)
__global__ __launch_bounds__(256) void k_final(
    const float* __restrict__ x3, const float* __restrict__ feats,
    const float* __restrict__ wf, const float* __restrict__ bf,
    const float* __restrict__ wr, const float* __restrict__ brs,
    float* __restrict__ out, int BN) {
  __shared__ float wtf[4096];  // wtf[i*64+o] = wf[o*64+i]
  __shared__ float wtr[4096];
  int t = threadIdx.x;
  for (int e = t; e < 4096; e += 256) {
    int o = e >> 6, i = e & 63;
    wtf[i * 64 + o] = wf[e];
    wtr[i * 64 + o] = wr[e];
  }
  __syncthreads();
  int p = blockIdx.x * 256 + t;
  if (p >= BN) return;
  float acc[64];
#pragma unroll
  for (int o = 0; o < 64; ++o) acc[o] = bf[o];
  const float* xr = x3 + (size_t)p * 64;
#pragma unroll 2
  for (int i = 0; i < 64; ++i) {
    float xi = xr[i];
    const float4* w4 = (const float4*)&wtf[i * 64];
#pragma unroll
    for (int q = 0; q < 16; ++q) {
      float4 wv = w4[q];
      acc[q * 4 + 0] = fmaf(xi, wv.x, acc[q * 4 + 0]);
      acc[q * 4 + 1] = fmaf(xi, wv.y, acc[q * 4 + 1]);
      acc[q * 4 + 2] = fmaf(xi, wv.z, acc[q * 4 + 2]);
      acc[q * 4 + 3] = fmaf(xi, wv.w, acc[q * 4 + 3]);
    }
  }
  float y[64];
#pragma unroll
  for (int o = 0; o < 64; ++o) y[o] = lrelu(acc[o]);
#pragma unroll
  for (int o = 0; o < 64; ++o) acc[o] = brs[o];
  const float* fr = feats + (size_t)p * 64;
#pragma unroll 2
  for (int i = 0; i < 64; ++i) {
    float xi = fr[i];
    const float4* w4 = (const float4*)&wtr[i * 64];
#pragma unroll
    for (int q = 0; q < 16; ++q) {
      float4 wv = w4[q];
      acc[q * 4 + 0] = fmaf(xi, wv.x, acc[q * 4 + 0]);
      acc[q * 4 + 1] = fmaf(xi, wv.y, acc[q * 4 + 1]);
      acc[q * 4 + 2] = fmaf(xi, wv.z, acc[q * 4 + 2]);
      acc[q * 4 + 3] = fmaf(xi, wv.w, acc[q * 4 + 3]);
    }
  }
  float4* op = (float4*)(out + (size_t)p * 64);
#pragma unroll
  for (int q = 0; q < 16; ++q) {
    float4 v;
    v.x = y[q * 4 + 0] + lrelu(acc[q * 4 + 0]);
    v.y = y[q * 4 + 1] + lrelu(acc[q * 4 + 1]);
    v.z = y[q * 4 + 2] + lrelu(acc[q * 4 + 2]);
    v.w = y[q * 4 + 3] + lrelu(acc[q * 4 + 3]);
    op[q] = v;
  }
}

extern "C" void kernel_launch(void* const* d_in, const int* in_sizes, int n_in,
                              void* d_out, int out_size, void* d_ws, size_t ws_size,
                              hipStream_t stream) {
  const float* pts    = (const float*)d_in[0];
  const float* feats  = (const float*)d_in[1];
  const int*   idx    = (const int*)d_in[2];
  const float* w_init = (const float*)d_in[3];
  const float* b_init = (const float*)d_in[4];
  const float* w_l1   = (const float*)d_in[5];
  const float* b_l1   = (const float*)d_in[6];
  const float* w_l2   = (const float*)d_in[7];
  const float* b_l2   = (const float*)d_in[8];
  const float* w_f    = (const float*)d_in[9];
  const float* b_f    = (const float*)d_in[10];
  const float* w_r    = (const float*)d_in[11];
  const float* b_r    = (const float*)d_in[12];
  float* out = (float*)d_out;

  int BN = in_sizes[2] / 32;  // B*N = 131072
  // ws layout: x2 (BN*32 f32 = 16 MB) | pts4 (BN*16B = 2 MB).  x1 lives in d_out.
  float* x2 = (float*)d_ws;
  float4* pts4 = (float4*)((char*)d_ws + (size_t)BN * 32 * sizeof(float));
  float* x1 = out;  // 8 MB of the 32 MB output buffer; dead before x3 is written

  int blocks_pt = (BN + 255) / 256;   // thread-per-point kernels
  int blocks_g = (BN + 63) / 64;      // 4-threads-per-point gather kernels

  k_init<<<blocks_pt, 256, 0, stream>>>(feats, w_init, b_init, x1, pts, pts4, BN);
  k_lfa<16, 16><<<blocks_g, 256, 0, stream>>>(pts4, x1, idx, w_l1, b_l1, x2, BN);
  k_lfa<32, 32><<<blocks_g, 256, 0, stream>>>(pts4, x2, idx, w_l2, b_l2, out, BN);
  k_final<<<blocks_pt, 256, 0, stream>>>(out, feats, w_f, b_f, w_r, b_r, out, BN);
}